// Round 8
// baseline (422.434 us; speedup 1.0000x reference)
//
#include <hip/hip_runtime.h>
#include <cstdint>

typedef float f32x4 __attribute__((ext_vector_type(4)));
typedef short bf16x8 __attribute__((ext_vector_type(8)));
typedef unsigned short u16x4 __attribute__((ext_vector_type(4)));
typedef unsigned uint4v __attribute__((ext_vector_type(4)));
typedef unsigned uint2v __attribute__((ext_vector_type(2)));

#define LOG2E 1.44269504088896340736f

#if __has_builtin(__builtin_amdgcn_exp2f)
#define EXP2(v) __builtin_amdgcn_exp2f(v)
#else
#define EXP2(v) exp2f(v)
#endif
#if __has_builtin(__builtin_amdgcn_logf)
#define LOG2F(v) __builtin_amdgcn_logf(v)
#else
#define LOG2F(v) __log2f(v)
#endif

// async global->LDS, 16B per lane, dest = wave-uniform base + lane*16
#define GLD16(gp, lp) __builtin_amdgcn_global_load_lds( \
    (const __attribute__((address_space(1))) unsigned*)(const void*)(gp), \
    (__attribute__((address_space(3))) unsigned*)(void*)(lp), 16, 0, 0)

// workspace byte offsets (all 16B-aligned)
enum : unsigned {
    WALL_OFF  = 0u,          // 192*256 bf16 (f rows pre-scaled by log2e)
    BALL_OFF  = 98304u,      // 192 f32 combined bias
    WVF_OFF   = 99072u,      // 256*128 bf16, fragment-major [cct][ks][lane][8]
    FF_OFF    = 164608u,     // 8*4096*32 bf16, frag-major [b][nt][lane][8]
    GF_OFF    = 2261760u,    // 8*4096*32 bf16, frag-major [b][mt][lane][8]
    HF_OFF    = 4358912u,    // 8*128*4096 bf16, frag-major [b][nt32][ct][lane][8]
    ZPART_OFF = 12878592u,   // 4*8*4096 f32 partial Z sums
    CTR_OFF   = 13402880u,   // 256 int completion counters (zeroed by k0)
    PART_OFF  = 13404928u,   // 8*NS*4096*128 bf16 partial O [b][nh][m][c]
};

static __device__ __forceinline__ unsigned short f2bf(float f) {
    unsigned u = __builtin_bit_cast(unsigned, f);
    u += 0x7fffu + ((u >> 16) & 1u);   // RNE
    return (unsigned short)(u >> 16);
}

// pack two f32 -> packed bf16 pair (round-to-nearest): 2 adds + 1 v_perm
static __device__ __forceinline__ unsigned pk_bf(float lo, float hi) {
    unsigned a = __builtin_bit_cast(unsigned, hi) + 0x8000u;
    unsigned b = __builtin_bit_cast(unsigned, lo) + 0x8000u;
    return __builtin_amdgcn_perm(a, b, 0x07060302u);
}

static __device__ __forceinline__ f32x4 mfma_bf16(bf16x8 a, bf16x8 b, f32x4 c) {
    return __builtin_amdgcn_mfma_f32_16x16x32_bf16(a, b, c, 0, 0, 0);
}

// ---- k0: pack weights to bf16 + zero completion counters ----
__global__ __launch_bounds__(256) void k0_pack(const float* __restrict__ wf,
                                               const float* __restrict__ bfv,
                                               const float* __restrict__ wg,
                                               const float* __restrict__ bg,
                                               const float* __restrict__ wh,
                                               const float* __restrict__ bh,
                                               const float* __restrict__ wv,
                                               unsigned char* __restrict__ ws) {
    unsigned idx = blockIdx.x * 256u + threadIdx.x;
    unsigned short* Wall = (unsigned short*)(ws + WALL_OFF);
    float* ball = (float*)(ws + BALL_OFF);
    unsigned short* wvf = (unsigned short*)(ws + WVF_OFF);
    if (idx < 49152u) {                    // Wall[k][c], k in [0,192)
        unsigned k = idx >> 8;
        float v;
        if (k < 32u)      v = wf[idx] * LOG2E;
        else if (k < 64u) v = wg[idx - 8192u];
        else              v = wh[idx - 16384u];
        Wall[idx] = f2bf(v);
    } else if (idx < 49344u) {             // ball[192]
        unsigned k = idx - 49152u;
        float v;
        if (k < 32u)      v = bfv[k] * LOG2E;
        else if (k < 64u) v = bg[k - 32u];
        else              v = bh[k - 64u];
        ball[k] = v;
    } else if (idx < 82112u) {             // Wv -> fragment-major bf16
        unsigned jj = idx - 49344u;        // 0..32767, row-major [cc 256][c 128]
        unsigned cc = jj >> 7, c = jj & 127u;
        unsigned cct = cc >> 4, lv = cc & 15u;
        unsigned ksv = c >> 5, qv = (c >> 3) & 3u, jv = c & 7u;
        wvf[(((cct * 4u + ksv) * 4u + qv) * 16u + lv) * 8u + jv] = f2bf(wv[jj]);
    } else if (idx < 82624u) {             // zero 512 ints of counter space
        ((int*)(ws + CTR_OFF))[idx - 82112u] = 0;
    }
}

// ---- k1: projections P = Wall(192x256) @ X_b(256x4096) + bias ----
__global__ __launch_bounds__(256) void k1_proj(const float* __restrict__ x,
                                               unsigned char* __restrict__ ws) {
    __shared__ unsigned XT[64 * 132];   // [n][cpair] packed bf16 pairs
    const int b = blockIdx.y;
    const int n0 = blockIdx.x * 64;
    const unsigned short* Wall = (const unsigned short*)(ws + WALL_OFF);
    const float* ball = (const float*)(ws + BALL_OFF);
    unsigned short* Ff = (unsigned short*)(ws + FF_OFF) + b * 131072;
    unsigned short* Gf = (unsigned short*)(ws + GF_OFF) + b * 131072;
    unsigned short* Hf = (unsigned short*)(ws + HF_OFF) + b * 524288;
    const int tid = threadIdx.x;
    const float* xb = x + b * (256 * 4096) + n0;
    {
        const int n4 = (tid & 15) * 4;
        const int crow = (tid >> 4) * 2;
        #pragma unroll
        for (int it = 0; it < 8; ++it) {
            const int c = crow + it * 32;
            const f32x4 r0 = *(const f32x4*)&xb[(size_t)c * 4096 + n4];
            const f32x4 r1 = *(const f32x4*)&xb[(size_t)(c + 1) * 4096 + n4];
            #pragma unroll
            for (int j = 0; j < 4; ++j)
                XT[(n4 + j) * 132 + (c >> 1)] = pk_bf(r0[j], r1[j]);
        }
    }
    __syncthreads();
    const int l = tid & 15, q = (tid >> 4) & 3, w = tid >> 6;
    const int nloc = w * 16 + l;
    const int ncol = n0 + nloc;
    bf16x8 bX[8];
    #pragma unroll
    for (int ks = 0; ks < 8; ++ks)
        bX[ks] = *(const bf16x8*)&XT[nloc * 132 + ks * 16 + q * 4];
    #pragma unroll
    for (int kt = 0; kt < 12; ++kt) {
        f32x4 acc = {0.f, 0.f, 0.f, 0.f};
        #pragma unroll
        for (int ks = 0; ks < 8; ++ks) {
            bf16x8 aW = *(const bf16x8*)&Wall[(kt * 16 + l) * 256 + ks * 32 + q * 8];
            acc = mfma_bf16(aW, bX[ks], acc);
        }
        const int kr0 = kt * 16 + q * 4;   // D: row k = q*4+r, col = l
        #pragma unroll
        for (int r = 0; r < 4; ++r) acc[r] += ball[kr0 + r];
        if (kt < 4) {
            const int kk = kt & 1;
            unsigned short* dst = (kt < 2) ? Ff : Gf;
            const int nt = ncol >> 4;
            const int qf = kk * 2 + (q >> 1), j0 = (q & 1) * 4;
            u16x4 pk;
            #pragma unroll
            for (int r = 0; r < 4; ++r) pk[r] = f2bf(acc[r]);
            *(u16x4*)&dst[(nt * 64 + qf * 16 + l) * 8 + j0] = pk;
        } else {
            const int ct = kt - 4;
            const int nt = ncol >> 5, qh = (ncol >> 3) & 3, jh = ncol & 7;
            #pragma unroll
            for (int r = 0; r < 4; ++r)
                Hf[((nt * 8 + ct) * 64 + qh * 16 + (q * 4 + r)) * 8 + jh] = f2bf(acc[r]);
        }
    }
}

// ---- k2: pass A — partial Z[n] over m-slice; wave owns n-sub 64 ----
__global__ __launch_bounds__(256) void k2_stats(unsigned char* __restrict__ ws) {
    const int b = blockIdx.y, zsl = blockIdx.z, tid = threadIdx.x;
    const int lane = tid & 63, l = tid & 15, q = (tid >> 4) & 3, w = tid >> 6;
    const unsigned short* Ff = (const unsigned short*)(ws + FF_OFF) + b * 131072;
    const unsigned short* Gf = (const unsigned short*)(ws + GF_OFF) + b * 131072;
    float* Zp = (float*)(ws + ZPART_OFF) + zsl * 32768 + b * 4096;
    const int n0 = blockIdx.x * 256 + w * 64;
    const int nt0 = n0 >> 4;
    bf16x8 aF[4];
    #pragma unroll
    for (int t = 0; t < 4; ++t)
        aF[t] = *(const bf16x8*)&Ff[((nt0 + t) * 64 + lane) * 8];
    f32x4 z[4];
    #pragma unroll
    for (int t = 0; t < 4; ++t) z[t] = (f32x4){0.f, 0.f, 0.f, 0.f};
    const int mt0 = zsl * 64;
    bf16x8 bG = *(const bf16x8*)&Gf[(mt0 * 64 + lane) * 8];
    for (int mt = 0; mt < 64; ++mt) {
        const bf16x8 g = bG;
        if (mt + 1 < 64)
            bG = *(const bf16x8*)&Gf[((mt0 + mt + 1) * 64 + lane) * 8];
        #pragma unroll
        for (int t = 0; t < 4; ++t) {
            f32x4 s = mfma_bf16(aF[t], g, (f32x4){0.f, 0.f, 0.f, 0.f});
            #pragma unroll
            for (int r = 0; r < 4; ++r)
                z[t][r] += EXP2(s[r]);
        }
    }
    #pragma unroll
    for (int off = 1; off < 16; off <<= 1)
        #pragma unroll
        for (int t = 0; t < 4; ++t)
            #pragma unroll
            for (int r = 0; r < 4; ++r)
                z[t][r] += __shfl_xor(z[t][r], off, 64);
    if (l == 0) {
        #pragma unroll
        for (int t = 0; t < 4; ++t)
            #pragma unroll
            for (int r = 0; r < 4; ++r)
                Zp[n0 + t * 16 + q * 4 + r] = z[t][r];
    }
}

// ---- k3: pass B fused — lsc prologue, attention K-loop, atomic last-block
//      combine + Wv projection + bias + residual ----
template<int NS>
__global__ __launch_bounds__(256, 4) void k3_attn(const float* __restrict__ x,
                                                  const float* __restrict__ bv,
                                                  const float* __restrict__ gamma,
                                                  float* __restrict__ out,
                                                  unsigned char* __restrict__ ws) {
    constexpr int NITER = 128 / NS;          // n-tiles (of 32) per block
    constexpr int NGRP = 8 * NS;             // (b, nh) groups
    constexpr int NQ = 4096 / NS;            // n-values per block
    __shared__ __align__(16) unsigned short HT[2][4096];    // 2 x 8KB
    __shared__ __align__(16) unsigned short FTs[2][1024];   // 2 x 2KB
    __shared__ __align__(16) float SC[NQ];                  // lsc slice
    __shared__ int lastFlag;
    const int tid = threadIdx.x;
    const int lane = tid & 63, l = tid & 15, q = (tid >> 4) & 3, w = tid >> 6;
    const int g = blockIdx.x % NGRP, bxm = blockIdx.x / NGRP;
    const int b = g / NS, nh = g % NS;
    const unsigned short* Ff = (const unsigned short*)(ws + FF_OFF) + b * 131072;
    const unsigned short* Gf = (const unsigned short*)(ws + GF_OFF) + b * 131072;
    const unsigned short* Hf = (const unsigned short*)(ws + HF_OFF) + b * 524288;
    const int mt0 = bxm * 8 + w * 2;             // wave's two m-frags (32 m)
    const bf16x8 bG0 = *(const bf16x8*)&Gf[(mt0 * 64 + lane) * 8];
    const bf16x8 bG1 = *(const bf16x8*)&Gf[((mt0 + 1) * 64 + lane) * 8];
    f32x4 acc0[8], acc1[8];
    #pragma unroll
    for (int ct = 0; ct < 8; ++ct) {
        acc0[ct] = (f32x4){0.f, 0.f, 0.f, 0.f};
        acc1[ct] = (f32x4){0.f, 0.f, 0.f, 0.f};
    }
    const bool qlo = q < 2;
    const int srcA = (q & 1) * 32 + l;
    const int srcB = srcA + 16;

    auto stage = [&](int i, int p) {
        const unsigned short* Hg = Hf + (size_t)(nh * NITER + i) * 4096;
        GLD16(Hg + ((w * 2 + 0) * 64 + lane) * 8, &HT[p][(w * 2 + 0) * 512]);
        GLD16(Hg + ((w * 2 + 1) * 64 + lane) * 8, &HT[p][(w * 2 + 1) * 512]);
        if (w < 2)
            GLD16(Ff + ((size_t)((nh * NITER + i) * 2 + w) * 64 + lane) * 8,
                  &FTs[p][w * 512]);
    };

    stage(0, 0);
    // lsc prologue (replaces k2b): SC[j] = -log2(sum of 4 Z partials)
    {
        const float* zp = (const float*)(ws + ZPART_OFF) + b * 4096 + nh * NQ;
        #pragma unroll
        for (int j = tid; j < NQ; j += 256) {
            const float s = zp[j] + zp[32768 + j] + zp[65536 + j] + zp[98304 + j];
            SC[j] = -LOG2F(s);
        }
    }

    for (int i = 0; i < NITER; ++i) {
        const int p = i & 1;
        __syncthreads();
        if (i + 1 < NITER) stage(i + 1, p ^ 1);
        const bf16x8 aF0 = *(const bf16x8*)&FTs[p][lane * 8];
        const bf16x8 aF1 = *(const bf16x8*)&FTs[p][512 + lane * 8];
        const f32x4 c0 = *(const f32x4*)&SC[i * 32 + q * 4];
        const f32x4 c1 = *(const f32x4*)&SC[i * 32 + 16 + q * 4];
        // S-MFMA with C = lsc[n]: e = exp2(s' - log2 Z) in (0, 1]
        f32x4 s0 = mfma_bf16(aF0, bG0, c0);
        f32x4 s1 = mfma_bf16(aF1, bG0, c1);
        f32x4 s2 = mfma_bf16(aF0, bG1, c0);
        f32x4 s3 = mfma_bf16(aF1, bG1, c1);
        f32x4 e0, e1, e2, e3;
        #pragma unroll
        for (int r = 0; r < 4; ++r) {
            e0[r] = EXP2(s0[r]);
            e1[r] = EXP2(s1[r]);
            e2[r] = EXP2(s2[r]);
            e3[r] = EXP2(s3[r]);
        }
        const unsigned a01 = pk_bf(e0[0], e0[1]), a23 = pk_bf(e0[2], e0[3]);
        const unsigned b01 = pk_bf(e1[0], e1[1]), b23 = pk_bf(e1[2], e1[3]);
        const unsigned g01 = pk_bf(e2[0], e2[1]), g23 = pk_bf(e2[2], e2[3]);
        const unsigned h01 = pk_bf(e3[0], e3[1]), h23 = pk_bf(e3[2], e3[3]);
        uint4v r0, r1;
        {
            int tA, tB;
            tA = __shfl((int)a01, srcA, 64); tB = __shfl((int)b01, srcA, 64);
            r0[0] = (unsigned)(qlo ? tA : tB);
            tA = __shfl((int)a23, srcA, 64); tB = __shfl((int)b23, srcA, 64);
            r0[1] = (unsigned)(qlo ? tA : tB);
            tA = __shfl((int)a01, srcB, 64); tB = __shfl((int)b01, srcB, 64);
            r0[2] = (unsigned)(qlo ? tA : tB);
            tA = __shfl((int)a23, srcB, 64); tB = __shfl((int)b23, srcB, 64);
            r0[3] = (unsigned)(qlo ? tA : tB);
            tA = __shfl((int)g01, srcA, 64); tB = __shfl((int)h01, srcA, 64);
            r1[0] = (unsigned)(qlo ? tA : tB);
            tA = __shfl((int)g23, srcA, 64); tB = __shfl((int)h23, srcA, 64);
            r1[1] = (unsigned)(qlo ? tA : tB);
            tA = __shfl((int)g01, srcB, 64); tB = __shfl((int)h01, srcB, 64);
            r1[2] = (unsigned)(qlo ? tA : tB);
            tA = __shfl((int)g23, srcB, 64); tB = __shfl((int)h23, srcB, 64);
            r1[3] = (unsigned)(qlo ? tA : tB);
        }
        const bf16x8 bE0 = __builtin_bit_cast(bf16x8, r0);
        const bf16x8 bE1 = __builtin_bit_cast(bf16x8, r1);
        #pragma unroll
        for (int ct = 0; ct < 8; ++ct) {
            const bf16x8 aH = *(const bf16x8*)&HT[p][ct * 512 + lane * 8];
            acc0[ct] = mfma_bf16(aH, bE0, acc0[ct]);
            acc1[ct] = mfma_bf16(aH, bE1, acc1[ct]);
        }
    }
    // partial O -> global bf16 [b][nh][m 4096][c 128]
    unsigned short* P = (unsigned short*)(ws + PART_OFF);
    const size_t mb = (size_t)(b * NS + nh) * 4096 + bxm * 128;
    #pragma unroll
    for (int ct = 0; ct < 8; ++ct) {
        uint2v p0, p1;
        p0[0] = pk_bf(acc0[ct][0], acc0[ct][1]);
        p0[1] = pk_bf(acc0[ct][2], acc0[ct][3]);
        p1[0] = pk_bf(acc1[ct][0], acc1[ct][1]);
        p1[1] = pk_bf(acc1[ct][2], acc1[ct][3]);
        *(uint2v*)&P[(mb + w * 32 + l) * 128 + ct * 16 + q * 4] = p0;
        *(uint2v*)&P[(mb + w * 32 + 16 + l) * 128 + ct * 16 + q * 4] = p1;
    }
    __syncthreads();            // drains the P stores (vmcnt(0)) for all waves
    if (tid == 0) {
        __threadfence();        // release: P visible device-wide
        int* ctr = (int*)(ws + CTR_OFF);
        const int old = atomicAdd(&ctr[b * 32 + bxm], 1);
        lastFlag = (old == NS - 1) ? 1 : 0;
    }
    __syncthreads();
    if (!lastFlag) return;
    __threadfence();            // acquire: see other blocks' P
    // ---- combine NS partials + Wv projection + bias + residual (128 m) ----
    const unsigned short* Pr = (const unsigned short*)(ws + PART_OFF);
    const unsigned short* Wvf = (const unsigned short*)(ws + WVF_OFF);
    const float gam = gamma[0];
    const float* xb = x + b * (256 * 4096);
    float* ob = out + b * (256 * 4096);
    #pragma unroll
    for (int msub = 0; msub < 2; ++msub) {
        const int mg = bxm * 128 + msub * 64 + w * 16 + l;
        bf16x8 bO[4];
        #pragma unroll
        for (int ks = 0; ks < 4; ++ks) {
            float lo[4] = {0.f, 0.f, 0.f, 0.f}, hi[4] = {0.f, 0.f, 0.f, 0.f};
            #pragma unroll
            for (int h = 0; h < NS; ++h) {
                const size_t bh = ((size_t)(b * NS + h) * 4096 + mg) * 128;
                const uint4v u = *(const uint4v*)&Pr[bh + ks * 32 + q * 8];
                #pragma unroll
                for (int j = 0; j < 4; ++j) {
                    lo[j] += __builtin_bit_cast(float, u[j] << 16);
                    hi[j] += __builtin_bit_cast(float, u[j] & 0xffff0000u);
                }
            }
            uint4v s;
            #pragma unroll
            for (int j = 0; j < 4; ++j) s[j] = pk_bf(lo[j], hi[j]);
            bO[ks] = __builtin_bit_cast(bf16x8, s);
        }
        #pragma unroll
        for (int cct = 0; cct < 16; ++cct) {
            f32x4 f = {0.f, 0.f, 0.f, 0.f};
            #pragma unroll
            for (int ks = 0; ks < 4; ++ks) {
                const bf16x8 aV = *(const bf16x8*)&Wvf[((cct * 4 + ks) * 64 + lane) * 8];
                f = mfma_bf16(aV, bO[ks], f);
            }
            #pragma unroll
            for (int r = 0; r < 4; ++r) {
                const int cc = cct * 16 + q * 4 + r;
                ob[cc * 4096 + mg] = xb[cc * 4096 + mg] + gam * (f[r] + bv[cc]);
            }
        }
    }
}

extern "C" void kernel_launch(void* const* d_in, const int* in_sizes, int n_in,
                              void* d_out, int out_size, void* d_ws, size_t ws_size,
                              hipStream_t stream) {
    const float* x   = (const float*)d_in[0];
    const float* wf  = (const float*)d_in[1];
    const float* bfv = (const float*)d_in[2];
    const float* wg  = (const float*)d_in[3];
    const float* bg  = (const float*)d_in[4];
    const float* wh  = (const float*)d_in[5];
    const float* bh  = (const float*)d_in[6];
    const float* wv  = (const float*)d_in[7];
    const float* bv  = (const float*)d_in[8];
    const float* gam = (const float*)d_in[9];
    float* out = (float*)d_out;
    unsigned char* ws = (unsigned char*)d_ws;
    (void)in_sizes; (void)n_in; (void)out_size;

    hipLaunchKernelGGL(k0_pack, dim3(322), dim3(256), 0, stream,
                       wf, bfv, wg, bg, wh, bh, wv, ws);
    hipLaunchKernelGGL(k1_proj, dim3(64, 8), dim3(256), 0, stream, x, ws);
    hipLaunchKernelGGL(k2_stats, dim3(16, 8, 4), dim3(256), 0, stream, ws);

    const size_t need4 = (size_t)PART_OFF + (size_t)8 * 4 * 4096 * 128 * 2;
    if (ws_size >= need4) {
        hipLaunchKernelGGL(HIP_KERNEL_NAME(k3_attn<4>), dim3(1024), dim3(256),
                           0, stream, x, bv, gam, out, ws);
    } else {
        hipLaunchKernelGGL(HIP_KERNEL_NAME(k3_attn<2>), dim3(512), dim3(256),
                           0, stream, x, bv, gam, out, ws);
    }
}

// Round 9
// 247.949 us; speedup vs baseline: 1.7037x; 1.7037x over previous
//
#include <hip/hip_runtime.h>
#include <cstdint>

typedef float f32x4 __attribute__((ext_vector_type(4)));
typedef short bf16x8 __attribute__((ext_vector_type(8)));
typedef unsigned short u16x4 __attribute__((ext_vector_type(4)));
typedef unsigned uint4v __attribute__((ext_vector_type(4)));
typedef unsigned uint2v __attribute__((ext_vector_type(2)));

#define LOG2E 1.44269504088896340736f

#if __has_builtin(__builtin_amdgcn_exp2f)
#define EXP2(v) __builtin_amdgcn_exp2f(v)
#else
#define EXP2(v) exp2f(v)
#endif
#if __has_builtin(__builtin_amdgcn_logf)
#define LOG2F(v) __builtin_amdgcn_logf(v)
#else
#define LOG2F(v) __log2f(v)
#endif

// async global->LDS, 16B per lane, dest = wave-uniform base + lane*16
#define GLD16(gp, lp) __builtin_amdgcn_global_load_lds( \
    (const __attribute__((address_space(1))) unsigned*)(const void*)(gp), \
    (__attribute__((address_space(3))) unsigned*)(void*)(lp), 16, 0, 0)

// workspace byte offsets (all 16B-aligned)
enum : unsigned {
    WALL_OFF  = 0u,          // 192*256 bf16 (f rows pre-scaled by log2e)
    BALL_OFF  = 98304u,      // 192 f32 combined bias
    WVF_OFF   = 99072u,      // 256*128 bf16, fragment-major [cct][ks][lane][8]
    FF_OFF    = 164608u,     // 8*4096*32 bf16, frag-major [b][nt][lane][8]
    GF_OFF    = 2261760u,    // 8*4096*32 bf16, frag-major [b][mt][lane][8]
    HF_OFF    = 4358912u,    // 8*128*4096 bf16, frag-major [b][nt32][ct][lane][8]
    ZPART_OFF = 12878592u,   // 4*8*4096 f32 partial Z sums
    PART_OFF  = 13404928u,   // 8*NS*4096*128 bf16 partial O [b][nh][m][c]
};

static __device__ __forceinline__ unsigned short f2bf(float f) {
    unsigned u = __builtin_bit_cast(unsigned, f);
    u += 0x7fffu + ((u >> 16) & 1u);   // RNE
    return (unsigned short)(u >> 16);
}

// pack two f32 -> packed bf16 pair (round-to-nearest): 2 adds + 1 v_perm
static __device__ __forceinline__ unsigned pk_bf(float lo, float hi) {
    unsigned a = __builtin_bit_cast(unsigned, hi) + 0x8000u;
    unsigned b = __builtin_bit_cast(unsigned, lo) + 0x8000u;
    return __builtin_amdgcn_perm(a, b, 0x07060302u);
}

static __device__ __forceinline__ f32x4 mfma_bf16(bf16x8 a, bf16x8 b, f32x4 c) {
    return __builtin_amdgcn_mfma_f32_16x16x32_bf16(a, b, c, 0, 0, 0);
}

// ---- k0: pack weights to bf16 into workspace ----
__global__ __launch_bounds__(256) void k0_pack(const float* __restrict__ wf,
                                               const float* __restrict__ bfv,
                                               const float* __restrict__ wg,
                                               const float* __restrict__ bg,
                                               const float* __restrict__ wh,
                                               const float* __restrict__ bh,
                                               const float* __restrict__ wv,
                                               unsigned char* __restrict__ ws) {
    unsigned idx = blockIdx.x * 256u + threadIdx.x;
    unsigned short* Wall = (unsigned short*)(ws + WALL_OFF);
    float* ball = (float*)(ws + BALL_OFF);
    unsigned short* wvf = (unsigned short*)(ws + WVF_OFF);
    if (idx < 49152u) {                    // Wall[k][c], k in [0,192)
        unsigned k = idx >> 8;
        float v;
        if (k < 32u)      v = wf[idx] * LOG2E;
        else if (k < 64u) v = wg[idx - 8192u];
        else              v = wh[idx - 16384u];
        Wall[idx] = f2bf(v);
    } else if (idx < 49344u) {             // ball[192]
        unsigned k = idx - 49152u;
        float v;
        if (k < 32u)      v = bfv[k] * LOG2E;
        else if (k < 64u) v = bg[k - 32u];
        else              v = bh[k - 64u];
        ball[k] = v;
    } else if (idx < 82112u) {             // Wv -> fragment-major bf16
        unsigned jj = idx - 49344u;        // 0..32767, row-major [cc 256][c 128]
        unsigned cc = jj >> 7, c = jj & 127u;
        unsigned cct = cc >> 4, lv = cc & 15u;
        unsigned ksv = c >> 5, qv = (c >> 3) & 3u, jv = c & 7u;
        wvf[(((cct * 4u + ksv) * 4u + qv) * 16u + lv) * 8u + jv] = f2bf(wv[jj]);
    }
}

// ---- k1: projections P = Wall(192x256) @ X_b(256x4096) + bias ----
__global__ __launch_bounds__(256) void k1_proj(const float* __restrict__ x,
                                               unsigned char* __restrict__ ws) {
    __shared__ unsigned XT[64 * 132];   // [n][cpair] packed bf16 pairs
    const int b = blockIdx.y;
    const int n0 = blockIdx.x * 64;
    const unsigned short* Wall = (const unsigned short*)(ws + WALL_OFF);
    const float* ball = (const float*)(ws + BALL_OFF);
    unsigned short* Ff = (unsigned short*)(ws + FF_OFF) + b * 131072;
    unsigned short* Gf = (unsigned short*)(ws + GF_OFF) + b * 131072;
    unsigned short* Hf = (unsigned short*)(ws + HF_OFF) + b * 524288;
    const int tid = threadIdx.x;
    const float* xb = x + b * (256 * 4096) + n0;
    {
        const int n4 = (tid & 15) * 4;
        const int crow = (tid >> 4) * 2;
        #pragma unroll
        for (int it = 0; it < 8; ++it) {
            const int c = crow + it * 32;
            const f32x4 r0 = *(const f32x4*)&xb[(size_t)c * 4096 + n4];
            const f32x4 r1 = *(const f32x4*)&xb[(size_t)(c + 1) * 4096 + n4];
            #pragma unroll
            for (int j = 0; j < 4; ++j)
                XT[(n4 + j) * 132 + (c >> 1)] = pk_bf(r0[j], r1[j]);
        }
    }
    __syncthreads();
    const int l = tid & 15, q = (tid >> 4) & 3, w = tid >> 6;
    const int nloc = w * 16 + l;
    const int ncol = n0 + nloc;
    bf16x8 bX[8];
    #pragma unroll
    for (int ks = 0; ks < 8; ++ks)
        bX[ks] = *(const bf16x8*)&XT[nloc * 132 + ks * 16 + q * 4];
    #pragma unroll
    for (int kt = 0; kt < 12; ++kt) {
        f32x4 acc = {0.f, 0.f, 0.f, 0.f};
        #pragma unroll
        for (int ks = 0; ks < 8; ++ks) {
            bf16x8 aW = *(const bf16x8*)&Wall[(kt * 16 + l) * 256 + ks * 32 + q * 8];
            acc = mfma_bf16(aW, bX[ks], acc);
        }
        const int kr0 = kt * 16 + q * 4;   // D: row k = q*4+r, col = l
        #pragma unroll
        for (int r = 0; r < 4; ++r) acc[r] += ball[kr0 + r];
        if (kt < 4) {
            const int kk = kt & 1;
            unsigned short* dst = (kt < 2) ? Ff : Gf;
            const int nt = ncol >> 4;
            const int qf = kk * 2 + (q >> 1), j0 = (q & 1) * 4;
            u16x4 pk;
            #pragma unroll
            for (int r = 0; r < 4; ++r) pk[r] = f2bf(acc[r]);
            *(u16x4*)&dst[(nt * 64 + qf * 16 + l) * 8 + j0] = pk;
        } else {
            const int ct = kt - 4;
            const int nt = ncol >> 5, qh = (ncol >> 3) & 3, jh = ncol & 7;
            #pragma unroll
            for (int r = 0; r < 4; ++r)
                Hf[((nt * 8 + ct) * 64 + qh * 16 + (q * 4 + r)) * 8 + jh] = f2bf(acc[r]);
        }
    }
}

// ---- k2: pass A — partial Z[n] over m-slice; wave owns n-sub 64 ----
__global__ __launch_bounds__(256) void k2_stats(unsigned char* __restrict__ ws) {
    const int b = blockIdx.y, zsl = blockIdx.z, tid = threadIdx.x;
    const int lane = tid & 63, l = tid & 15, q = (tid >> 4) & 3, w = tid >> 6;
    const unsigned short* Ff = (const unsigned short*)(ws + FF_OFF) + b * 131072;
    const unsigned short* Gf = (const unsigned short*)(ws + GF_OFF) + b * 131072;
    float* Zp = (float*)(ws + ZPART_OFF) + zsl * 32768 + b * 4096;
    const int n0 = blockIdx.x * 256 + w * 64;
    const int nt0 = n0 >> 4;
    bf16x8 aF[4];
    #pragma unroll
    for (int t = 0; t < 4; ++t)
        aF[t] = *(const bf16x8*)&Ff[((nt0 + t) * 64 + lane) * 8];
    f32x4 z[4];
    #pragma unroll
    for (int t = 0; t < 4; ++t) z[t] = (f32x4){0.f, 0.f, 0.f, 0.f};
    const int mt0 = zsl * 64;
    bf16x8 bG = *(const bf16x8*)&Gf[(mt0 * 64 + lane) * 8];
    for (int mt = 0; mt < 64; ++mt) {
        const bf16x8 g = bG;
        if (mt + 1 < 64)
            bG = *(const bf16x8*)&Gf[((mt0 + mt + 1) * 64 + lane) * 8];
        #pragma unroll
        for (int t = 0; t < 4; ++t) {
            f32x4 s = mfma_bf16(aF[t], g, (f32x4){0.f, 0.f, 0.f, 0.f});
            #pragma unroll
            for (int r = 0; r < 4; ++r)
                z[t][r] += EXP2(s[r]);
        }
    }
    #pragma unroll
    for (int off = 1; off < 16; off <<= 1)
        #pragma unroll
        for (int t = 0; t < 4; ++t)
            #pragma unroll
            for (int r = 0; r < 4; ++r)
                z[t][r] += __shfl_xor(z[t][r], off, 64);
    if (l == 0) {
        #pragma unroll
        for (int t = 0; t < 4; ++t)
            #pragma unroll
            for (int r = 0; r < 4; ++r)
                Zp[n0 + t * 16 + q * 4 + r] = z[t][r];
    }
}

// ---- k3: pass B — m-tile 128, n-split NS; lsc prologue; partial O out ----
template<int NS>
__global__ __launch_bounds__(256, 4) void k3_attn(unsigned char* __restrict__ ws) {
    constexpr int NITER = 128 / NS;          // n-tiles (of 32) per block
    constexpr int NGRP = 8 * NS;             // (b, nh) groups
    constexpr int NQ = 4096 / NS;            // n-values per block
    __shared__ __align__(16) unsigned short HT[2][4096];    // 2 x 8KB
    __shared__ __align__(16) unsigned short FTs[2][1024];   // 2 x 2KB
    __shared__ __align__(16) float SC[NQ];                  // lsc slice
    const int tid = threadIdx.x;
    const int lane = tid & 63, l = tid & 15, q = (tid >> 4) & 3, w = tid >> 6;
    const int g = blockIdx.x % NGRP, bxm = blockIdx.x / NGRP;
    const int b = g / NS, nh = g % NS;
    const unsigned short* Ff = (const unsigned short*)(ws + FF_OFF) + b * 131072;
    const unsigned short* Gf = (const unsigned short*)(ws + GF_OFF) + b * 131072;
    const unsigned short* Hf = (const unsigned short*)(ws + HF_OFF) + b * 524288;
    const int mt0 = bxm * 8 + w * 2;             // wave's two m-frags (32 m)
    const bf16x8 bG0 = *(const bf16x8*)&Gf[(mt0 * 64 + lane) * 8];
    const bf16x8 bG1 = *(const bf16x8*)&Gf[((mt0 + 1) * 64 + lane) * 8];
    f32x4 acc0[8], acc1[8];
    #pragma unroll
    for (int ct = 0; ct < 8; ++ct) {
        acc0[ct] = (f32x4){0.f, 0.f, 0.f, 0.f};
        acc1[ct] = (f32x4){0.f, 0.f, 0.f, 0.f};
    }
    const bool qlo = q < 2;
    const int srcA = (q & 1) * 32 + l;
    const int srcB = srcA + 16;

    auto stage = [&](int i, int p) {
        const unsigned short* Hg = Hf + (size_t)(nh * NITER + i) * 4096;
        GLD16(Hg + ((w * 2 + 0) * 64 + lane) * 8, &HT[p][(w * 2 + 0) * 512]);
        GLD16(Hg + ((w * 2 + 1) * 64 + lane) * 8, &HT[p][(w * 2 + 1) * 512]);
        if (w < 2)
            GLD16(Ff + ((size_t)((nh * NITER + i) * 2 + w) * 64 + lane) * 8,
                  &FTs[p][w * 512]);
    };

    stage(0, 0);
    // lsc prologue (replaces k2b): SC[j] = -log2(sum of 4 Z partials)
    {
        const float* zp = (const float*)(ws + ZPART_OFF) + b * 4096 + nh * NQ;
        #pragma unroll
        for (int j = tid; j < NQ; j += 256) {
            const float s = zp[j] + zp[32768 + j] + zp[65536 + j] + zp[98304 + j];
            SC[j] = -LOG2F(s);
        }
    }

    for (int i = 0; i < NITER; ++i) {
        const int p = i & 1;
        __syncthreads();
        if (i + 1 < NITER) stage(i + 1, p ^ 1);
        const bf16x8 aF0 = *(const bf16x8*)&FTs[p][lane * 8];
        const bf16x8 aF1 = *(const bf16x8*)&FTs[p][512 + lane * 8];
        const f32x4 c0 = *(const f32x4*)&SC[i * 32 + q * 4];
        const f32x4 c1 = *(const f32x4*)&SC[i * 32 + 16 + q * 4];
        // S-MFMA with C = lsc[n]: e = exp2(s' - log2 Z) in (0, 1]
        f32x4 s0 = mfma_bf16(aF0, bG0, c0);
        f32x4 s1 = mfma_bf16(aF1, bG0, c1);
        f32x4 s2 = mfma_bf16(aF0, bG1, c0);
        f32x4 s3 = mfma_bf16(aF1, bG1, c1);
        f32x4 e0, e1, e2, e3;
        #pragma unroll
        for (int r = 0; r < 4; ++r) {
            e0[r] = EXP2(s0[r]);
            e1[r] = EXP2(s1[r]);
            e2[r] = EXP2(s2[r]);
            e3[r] = EXP2(s3[r]);
        }
        const unsigned a01 = pk_bf(e0[0], e0[1]), a23 = pk_bf(e0[2], e0[3]);
        const unsigned b01 = pk_bf(e1[0], e1[1]), b23 = pk_bf(e1[2], e1[3]);
        const unsigned g01 = pk_bf(e2[0], e2[1]), g23 = pk_bf(e2[2], e2[3]);
        const unsigned h01 = pk_bf(e3[0], e3[1]), h23 = pk_bf(e3[2], e3[3]);
        uint4v r0, r1;
        {
            int tA, tB;
            tA = __shfl((int)a01, srcA, 64); tB = __shfl((int)b01, srcA, 64);
            r0[0] = (unsigned)(qlo ? tA : tB);
            tA = __shfl((int)a23, srcA, 64); tB = __shfl((int)b23, srcA, 64);
            r0[1] = (unsigned)(qlo ? tA : tB);
            tA = __shfl((int)a01, srcB, 64); tB = __shfl((int)b01, srcB, 64);
            r0[2] = (unsigned)(qlo ? tA : tB);
            tA = __shfl((int)a23, srcB, 64); tB = __shfl((int)b23, srcB, 64);
            r0[3] = (unsigned)(qlo ? tA : tB);
            tA = __shfl((int)g01, srcA, 64); tB = __shfl((int)h01, srcA, 64);
            r1[0] = (unsigned)(qlo ? tA : tB);
            tA = __shfl((int)g23, srcA, 64); tB = __shfl((int)h23, srcA, 64);
            r1[1] = (unsigned)(qlo ? tA : tB);
            tA = __shfl((int)g01, srcB, 64); tB = __shfl((int)h01, srcB, 64);
            r1[2] = (unsigned)(qlo ? tA : tB);
            tA = __shfl((int)g23, srcB, 64); tB = __shfl((int)h23, srcB, 64);
            r1[3] = (unsigned)(qlo ? tA : tB);
        }
        const bf16x8 bE0 = __builtin_bit_cast(bf16x8, r0);
        const bf16x8 bE1 = __builtin_bit_cast(bf16x8, r1);
        #pragma unroll
        for (int ct = 0; ct < 8; ++ct) {
            const bf16x8 aH = *(const bf16x8*)&HT[p][ct * 512 + lane * 8];
            acc0[ct] = mfma_bf16(aH, bE0, acc0[ct]);
            acc1[ct] = mfma_bf16(aH, bE1, acc1[ct]);
        }
    }
    // partial O -> global bf16 [b][nh][m 4096][c 128]
    unsigned short* P = (unsigned short*)(ws + PART_OFF);
    const size_t mb = (size_t)(b * NS + nh) * 4096 + bxm * 128;
    #pragma unroll
    for (int ct = 0; ct < 8; ++ct) {
        uint2v p0, p1;
        p0[0] = pk_bf(acc0[ct][0], acc0[ct][1]);
        p0[1] = pk_bf(acc0[ct][2], acc0[ct][3]);
        p1[0] = pk_bf(acc1[ct][0], acc1[ct][1]);
        p1[1] = pk_bf(acc1[ct][2], acc1[ct][3]);
        *(uint2v*)&P[(mb + w * 32 + l) * 128 + ct * 16 + q * 4] = p0;
        *(uint2v*)&P[(mb + w * 32 + 16 + l) * 128 + ct * 16 + q * 4] = p1;
    }
}

// ---- k4: combine NS partials + Wv projection + bias + residual ----
template<int NS>
__global__ __launch_bounds__(256) void k4_out(const float* __restrict__ x,
                                              const float* __restrict__ bv,
                                              const float* __restrict__ gamma,
                                              float* __restrict__ out,
                                              unsigned char* __restrict__ ws) {
    const int b = blockIdx.y, tid = threadIdx.x;
    const int lane = tid & 63, l = tid & 15, q = (tid >> 4) & 3, w = tid >> 6;
    const unsigned short* P = (const unsigned short*)(ws + PART_OFF);
    const unsigned short* Wvf = (const unsigned short*)(ws + WVF_OFF);
    const int mg = blockIdx.x * 64 + w * 16 + l;
    bf16x8 bO[4];
    #pragma unroll
    for (int ks = 0; ks < 4; ++ks) {
        float lo[4] = {0.f, 0.f, 0.f, 0.f}, hi[4] = {0.f, 0.f, 0.f, 0.f};
        #pragma unroll
        for (int h = 0; h < NS; ++h) {
            const size_t bh = ((size_t)(b * NS + h) * 4096 + mg) * 128;
            const uint4v u = *(const uint4v*)&P[bh + ks * 32 + q * 8];
            #pragma unroll
            for (int j = 0; j < 4; ++j) {
                lo[j] += __builtin_bit_cast(float, u[j] << 16);
                hi[j] += __builtin_bit_cast(float, u[j] & 0xffff0000u);
            }
        }
        uint4v s;
        #pragma unroll
        for (int j = 0; j < 4; ++j) s[j] = pk_bf(lo[j], hi[j]);
        bO[ks] = __builtin_bit_cast(bf16x8, s);
    }
    const float gam = gamma[0];
    const float* xb = x + b * (256 * 4096);
    float* ob = out + b * (256 * 4096);
    #pragma unroll
    for (int cct = 0; cct < 16; ++cct) {
        f32x4 f = {0.f, 0.f, 0.f, 0.f};
        #pragma unroll
        for (int ks = 0; ks < 4; ++ks) {
            const bf16x8 aV = *(const bf16x8*)&Wvf[((cct * 4 + ks) * 64 + lane) * 8];
            f = mfma_bf16(aV, bO[ks], f);
        }
        #pragma unroll
        for (int r = 0; r < 4; ++r) {
            const int cc = cct * 16 + q * 4 + r;
            ob[cc * 4096 + mg] = xb[cc * 4096 + mg] + gam * (f[r] + bv[cc]);
        }
    }
}

extern "C" void kernel_launch(void* const* d_in, const int* in_sizes, int n_in,
                              void* d_out, int out_size, void* d_ws, size_t ws_size,
                              hipStream_t stream) {
    const float* x   = (const float*)d_in[0];
    const float* wf  = (const float*)d_in[1];
    const float* bfv = (const float*)d_in[2];
    const float* wg  = (const float*)d_in[3];
    const float* bg  = (const float*)d_in[4];
    const float* wh  = (const float*)d_in[5];
    const float* bh  = (const float*)d_in[6];
    const float* wv  = (const float*)d_in[7];
    const float* bv  = (const float*)d_in[8];
    const float* gam = (const float*)d_in[9];
    float* out = (float*)d_out;
    unsigned char* ws = (unsigned char*)d_ws;
    (void)in_sizes; (void)n_in; (void)out_size;

    hipLaunchKernelGGL(k0_pack, dim3(321), dim3(256), 0, stream,
                       wf, bfv, wg, bg, wh, bh, wv, ws);
    hipLaunchKernelGGL(k1_proj, dim3(64, 8), dim3(256), 0, stream, x, ws);
    hipLaunchKernelGGL(k2_stats, dim3(16, 8, 4), dim3(256), 0, stream, ws);

    const size_t base = (size_t)PART_OFF;
    const size_t per  = (size_t)8 * 4096 * 128 * 2;   // bytes per NS slice
    if (ws_size >= base + 8 * per) {
        hipLaunchKernelGGL(HIP_KERNEL_NAME(k3_attn<8>), dim3(2048), dim3(256),
                           0, stream, ws);
        hipLaunchKernelGGL(HIP_KERNEL_NAME(k4_out<8>), dim3(64, 8), dim3(256),
                           0, stream, x, bv, gam, out, ws);
    } else if (ws_size >= base + 4 * per) {
        hipLaunchKernelGGL(HIP_KERNEL_NAME(k3_attn<4>), dim3(1024), dim3(256),
                           0, stream, ws);
        hipLaunchKernelGGL(HIP_KERNEL_NAME(k4_out<4>), dim3(64, 8), dim3(256),
                           0, stream, x, bv, gam, out, ws);
    } else {
        hipLaunchKernelGGL(HIP_KERNEL_NAME(k3_attn<2>), dim3(512), dim3(256),
                           0, stream, ws);
        hipLaunchKernelGGL(HIP_KERNEL_NAME(k4_out<2>), dim3(64, 8), dim3(256),
                           0, stream, x, bv, gam, out, ws);
    }
}

// Round 11
// 211.004 us; speedup vs baseline: 2.0020x; 1.1751x over previous
//
#include <hip/hip_runtime.h>
#include <cstdint>

typedef float f32x4 __attribute__((ext_vector_type(4)));
typedef short bf16x8 __attribute__((ext_vector_type(8)));
typedef short bf16x4 __attribute__((ext_vector_type(4)));
typedef unsigned short u16x4 __attribute__((ext_vector_type(4)));
typedef unsigned uint4v __attribute__((ext_vector_type(4)));
typedef unsigned uint2v __attribute__((ext_vector_type(2)));

#define LOG2E 1.44269504088896340736f

#if __has_builtin(__builtin_amdgcn_exp2f)
#define EXP2(v) __builtin_amdgcn_exp2f(v)
#else
#define EXP2(v) exp2f(v)
#endif
#if __has_builtin(__builtin_amdgcn_logf)
#define LOG2F(v) __builtin_amdgcn_logf(v)
#else
#define LOG2F(v) __log2f(v)
#endif

// K=16 bf16 MFMA: B-frag layout (k=q*4+j) matches S-output C-layout exactly,
// eliminating the 16 ds_bpermute per k3 iteration (LDS-pipe bottleneck).
#if __has_builtin(__builtin_amdgcn_mfma_f32_16x16x16bf16_1k)
#define HK16 1
static __device__ __forceinline__ f32x4 mfma16(bf16x4 a, bf16x4 b, f32x4 c) {
    return __builtin_amdgcn_mfma_f32_16x16x16bf16_1k(a, b, c, 0, 0, 0);
}
#else
#define HK16 0
#endif

// async global->LDS, 16B per lane, dest = wave-uniform base + lane*16
#define GLD16(gp, lp) __builtin_amdgcn_global_load_lds( \
    (const __attribute__((address_space(1))) unsigned*)(const void*)(gp), \
    (__attribute__((address_space(3))) unsigned*)(void*)(lp), 16, 0, 0)

// workspace byte offsets (all 16B-aligned)
enum : unsigned {
    WALL_OFF  = 0u,          // 192*256 bf16 (f rows pre-scaled by log2e)
    BALL_OFF  = 98304u,      // 192 f32 combined bias
    WVF_OFF   = 99072u,      // 256*128 bf16, fragment-major [cct][ks][lane][8]
    FF_OFF    = 164608u,     // 8*4096*32 bf16, frag-major [b][nt][lane][8]
    GF_OFF    = 2261760u,    // 8*4096*32 bf16, frag-major [b][mt][lane][8]
    HF_OFF    = 4358912u,    // 8*128*4096 bf16 [b][nt32][ct][lane][halves]
    ZPART_OFF = 12878592u,   // 4*8*4096 f32 partial Z sums
    PART_OFF  = 13404928u,   // 8*NS*4096*128 bf16 partial O [b][nh][m][c]
};

static __device__ __forceinline__ unsigned short f2bf(float f) {
    unsigned u = __builtin_bit_cast(unsigned, f);
    u += 0x7fffu + ((u >> 16) & 1u);   // RNE
    return (unsigned short)(u >> 16);
}

// pack two f32 -> packed bf16 pair (round-to-nearest): 2 adds + 1 v_perm
static __device__ __forceinline__ unsigned pk_bf(float lo, float hi) {
    unsigned a = __builtin_bit_cast(unsigned, hi) + 0x8000u;
    unsigned b = __builtin_bit_cast(unsigned, lo) + 0x8000u;
    return __builtin_amdgcn_perm(a, b, 0x07060302u);
}

static __device__ __forceinline__ f32x4 mfma_bf16(bf16x8 a, bf16x8 b, f32x4 c) {
    return __builtin_amdgcn_mfma_f32_16x16x32_bf16(a, b, c, 0, 0, 0);
}

// ---- k0: pack weights to bf16 into workspace ----
__global__ __launch_bounds__(256) void k0_pack(const float* __restrict__ wf,
                                               const float* __restrict__ bfv,
                                               const float* __restrict__ wg,
                                               const float* __restrict__ bg,
                                               const float* __restrict__ wh,
                                               const float* __restrict__ bh,
                                               const float* __restrict__ wv,
                                               unsigned char* __restrict__ ws) {
    unsigned idx = blockIdx.x * 256u + threadIdx.x;
    unsigned short* Wall = (unsigned short*)(ws + WALL_OFF);
    float* ball = (float*)(ws + BALL_OFF);
    unsigned short* wvf = (unsigned short*)(ws + WVF_OFF);
    if (idx < 49152u) {                    // Wall[k][c], k in [0,192)
        unsigned k = idx >> 8;
        float v;
        if (k < 32u)      v = wf[idx] * LOG2E;
        else if (k < 64u) v = wg[idx - 8192u];
        else              v = wh[idx - 16384u];
        Wall[idx] = f2bf(v);
    } else if (idx < 49344u) {             // ball[192]
        unsigned k = idx - 49152u;
        float v;
        if (k < 32u)      v = bfv[k] * LOG2E;
        else if (k < 64u) v = bg[k - 32u];
        else              v = bh[k - 64u];
        ball[k] = v;
    } else if (idx < 82112u) {             // Wv -> fragment-major bf16
        unsigned jj = idx - 49344u;        // 0..32767, row-major [cc 256][c 128]
        unsigned cc = jj >> 7, c = jj & 127u;
        unsigned cct = cc >> 4, lv = cc & 15u;
        unsigned ksv = c >> 5, qv = (c >> 3) & 3u, jv = c & 7u;
        wvf[(((cct * 4u + ksv) * 4u + qv) * 16u + lv) * 8u + jv] = f2bf(wv[jj]);
    }
}

// ---- k1: projections P = Wall(192x256) @ X_b(256x4096) + bias ----
__global__ __launch_bounds__(256) void k1_proj(const float* __restrict__ x,
                                               unsigned char* __restrict__ ws) {
    __shared__ unsigned XT[64 * 132];   // [n][cpair] packed bf16 pairs
    const int b = blockIdx.y;
    const int n0 = blockIdx.x * 64;
    const unsigned short* Wall = (const unsigned short*)(ws + WALL_OFF);
    const float* ball = (const float*)(ws + BALL_OFF);
    unsigned short* Ff = (unsigned short*)(ws + FF_OFF) + b * 131072;
    unsigned short* Gf = (unsigned short*)(ws + GF_OFF) + b * 131072;
    unsigned short* Hf = (unsigned short*)(ws + HF_OFF) + b * 524288;
    const int tid = threadIdx.x;
    const float* xb = x + b * (256 * 4096) + n0;
    {
        const int n4 = (tid & 15) * 4;
        const int crow = (tid >> 4) * 2;
        #pragma unroll
        for (int it = 0; it < 8; ++it) {
            const int c = crow + it * 32;
            const f32x4 r0 = *(const f32x4*)&xb[(size_t)c * 4096 + n4];
            const f32x4 r1 = *(const f32x4*)&xb[(size_t)(c + 1) * 4096 + n4];
            #pragma unroll
            for (int j = 0; j < 4; ++j)
                XT[(n4 + j) * 132 + (c >> 1)] = pk_bf(r0[j], r1[j]);
        }
    }
    __syncthreads();
    const int l = tid & 15, q = (tid >> 4) & 3, w = tid >> 6;
    const int nloc = w * 16 + l;
    const int ncol = n0 + nloc;
    bf16x8 bX[8];
    #pragma unroll
    for (int ks = 0; ks < 8; ++ks)
        bX[ks] = *(const bf16x8*)&XT[nloc * 132 + ks * 16 + q * 4];
    #pragma unroll
    for (int kt = 0; kt < 12; ++kt) {
        f32x4 acc = {0.f, 0.f, 0.f, 0.f};
        #pragma unroll
        for (int ks = 0; ks < 8; ++ks) {
            bf16x8 aW = *(const bf16x8*)&Wall[(kt * 16 + l) * 256 + ks * 32 + q * 8];
            acc = mfma_bf16(aW, bX[ks], acc);
        }
        const int kr0 = kt * 16 + q * 4;   // D: row k = q*4+r, col = l
        #pragma unroll
        for (int r = 0; r < 4; ++r) acc[r] += ball[kr0 + r];
        if (kt < 4) {
            const int kk = kt & 1;
            unsigned short* dst = (kt < 2) ? Ff : Gf;
            const int nt = ncol >> 4;
            const int qf = kk * 2 + (q >> 1), j0 = (q & 1) * 4;
            u16x4 pk;
            #pragma unroll
            for (int r = 0; r < 4; ++r) pk[r] = f2bf(acc[r]);
            *(u16x4*)&dst[(nt * 64 + qf * 16 + l) * 8 + j0] = pk;
        } else {
            const int ct = kt - 4;
            const int nt = ncol >> 5;
#if HK16
            // layout: [nt][ct][lane = qn*16 + (c&15)][half*4 + jn]
            const int qn = (ncol >> 2) & 3, jn = ncol & 3, half = (ncol >> 4) & 1;
            #pragma unroll
            for (int r = 0; r < 4; ++r)
                Hf[((nt * 8 + ct) * 64 + qn * 16 + (q * 4 + r)) * 8 + half * 4 + jn]
                    = f2bf(acc[r]);
#else
            // layout for K=32 A-frags: [nt][ct][lane = qh*16 + (c&15)][jh]
            const int qh = (ncol >> 3) & 3, jh = ncol & 7;
            #pragma unroll
            for (int r = 0; r < 4; ++r)
                Hf[((nt * 8 + ct) * 64 + qh * 16 + (q * 4 + r)) * 8 + jh] = f2bf(acc[r]);
#endif
        }
    }
}

// ---- k2: pass A — partial Z[n] over m-slice; wave owns n-sub 64 ----
__global__ __launch_bounds__(256) void k2_stats(unsigned char* __restrict__ ws) {
    const int b = blockIdx.y, zsl = blockIdx.z, tid = threadIdx.x;
    const int lane = tid & 63, l = tid & 15, q = (tid >> 4) & 3, w = tid >> 6;
    const unsigned short* Ff = (const unsigned short*)(ws + FF_OFF) + b * 131072;
    const unsigned short* Gf = (const unsigned short*)(ws + GF_OFF) + b * 131072;
    float* Zp = (float*)(ws + ZPART_OFF) + zsl * 32768 + b * 4096;
    const int n0 = blockIdx.x * 256 + w * 64;
    const int nt0 = n0 >> 4;
    bf16x8 aF[4];
    #pragma unroll
    for (int t = 0; t < 4; ++t)
        aF[t] = *(const bf16x8*)&Ff[((nt0 + t) * 64 + lane) * 8];
    f32x4 z[4];
    #pragma unroll
    for (int t = 0; t < 4; ++t) z[t] = (f32x4){0.f, 0.f, 0.f, 0.f};
    const int mt0 = zsl * 64;
    bf16x8 bG = *(const bf16x8*)&Gf[(mt0 * 64 + lane) * 8];
    for (int mt = 0; mt < 64; ++mt) {
        const bf16x8 g = bG;
        if (mt + 1 < 64)
            bG = *(const bf16x8*)&Gf[((mt0 + mt + 1) * 64 + lane) * 8];
        #pragma unroll
        for (int t = 0; t < 4; ++t) {
            f32x4 s = mfma_bf16(aF[t], g, (f32x4){0.f, 0.f, 0.f, 0.f});
            #pragma unroll
            for (int r = 0; r < 4; ++r)
                z[t][r] += EXP2(s[r]);
        }
    }
    #pragma unroll
    for (int off = 1; off < 16; off <<= 1)
        #pragma unroll
        for (int t = 0; t < 4; ++t)
            #pragma unroll
            for (int r = 0; r < 4; ++r)
                z[t][r] += __shfl_xor(z[t][r], off, 64);
    if (l == 0) {
        #pragma unroll
        for (int t = 0; t < 4; ++t)
            #pragma unroll
            for (int r = 0; r < 4; ++r)
                Zp[n0 + t * 16 + q * 4 + r] = z[t][r];
    }
}

// ---- k3: pass B — m-tile 128, n-split NS; lsc-in-C; K=16 PV (no shuffles) ----
template<int NS>
__global__ __launch_bounds__(256, 4) void k3_attn(unsigned char* __restrict__ ws) {
    constexpr int NITER = 128 / NS;          // n-tiles (of 32) per block
    constexpr int NGRP = 8 * NS;             // (b, nh) groups
    constexpr int NQ = 4096 / NS;            // n-values per block
    __shared__ __align__(16) unsigned short HT[2][4096];    // 2 x 8KB
    __shared__ __align__(16) unsigned short FTs[2][1024];   // 2 x 2KB
    __shared__ __align__(16) float SC[NQ];                  // lsc slice
    const int tid = threadIdx.x;
    const int lane = tid & 63, l = tid & 15, q = (tid >> 4) & 3, w = tid >> 6;
    const int g = blockIdx.x % NGRP, bxm = blockIdx.x / NGRP;
    const int b = g / NS, nh = g % NS;
    const unsigned short* Ff = (const unsigned short*)(ws + FF_OFF) + b * 131072;
    const unsigned short* Gf = (const unsigned short*)(ws + GF_OFF) + b * 131072;
    const unsigned short* Hf = (const unsigned short*)(ws + HF_OFF) + b * 524288;
    const int mt0 = bxm * 8 + w * 2;             // wave's two m-frags (32 m)
    const bf16x8 bG0 = *(const bf16x8*)&Gf[(mt0 * 64 + lane) * 8];
    const bf16x8 bG1 = *(const bf16x8*)&Gf[((mt0 + 1) * 64 + lane) * 8];
    f32x4 acc0[8], acc1[8];
    #pragma unroll
    for (int ct = 0; ct < 8; ++ct) {
        acc0[ct] = (f32x4){0.f, 0.f, 0.f, 0.f};
        acc1[ct] = (f32x4){0.f, 0.f, 0.f, 0.f};
    }
#if !HK16
    const bool qlo = q < 2;
    const int srcA = (q & 1) * 32 + l;
    const int srcB = srcA + 16;
#endif

    auto stage = [&](int i, int p) {
        const unsigned short* Hg = Hf + (size_t)(nh * NITER + i) * 4096;
        GLD16(Hg + ((w * 2 + 0) * 64 + lane) * 8, &HT[p][(w * 2 + 0) * 512]);
        GLD16(Hg + ((w * 2 + 1) * 64 + lane) * 8, &HT[p][(w * 2 + 1) * 512]);
        if (w < 2)
            GLD16(Ff + ((size_t)((nh * NITER + i) * 2 + w) * 64 + lane) * 8,
                  &FTs[p][w * 512]);
    };

    stage(0, 0);
    // lsc prologue: SC[j] = -log2(sum of 4 Z partials)
    {
        const float* zp = (const float*)(ws + ZPART_OFF) + b * 4096 + nh * NQ;
        #pragma unroll
        for (int j = tid; j < NQ; j += 256) {
            const float s = zp[j] + zp[32768 + j] + zp[65536 + j] + zp[98304 + j];
            SC[j] = -LOG2F(s);
        }
    }

    for (int i = 0; i < NITER; ++i) {
        const int p = i & 1;
        __syncthreads();
        if (i + 1 < NITER) stage(i + 1, p ^ 1);
        const bf16x8 aF0 = *(const bf16x8*)&FTs[p][lane * 8];
        const bf16x8 aF1 = *(const bf16x8*)&FTs[p][512 + lane * 8];
        const f32x4 c0 = *(const f32x4*)&SC[i * 32 + q * 4];
        const f32x4 c1 = *(const f32x4*)&SC[i * 32 + 16 + q * 4];
        // S-MFMA with C = lsc[n]: e = exp2(s' - log2 Z) in (0, 1]
        f32x4 s0 = mfma_bf16(aF0, bG0, c0);   // (half0, m0)
        f32x4 s1 = mfma_bf16(aF1, bG0, c1);   // (half1, m0)
        f32x4 s2 = mfma_bf16(aF0, bG1, c0);   // (half0, m1)
        f32x4 s3 = mfma_bf16(aF1, bG1, c1);   // (half1, m1)
        f32x4 e0, e1, e2, e3;
        #pragma unroll
        for (int r = 0; r < 4; ++r) {
            e0[r] = EXP2(s0[r]);
            e1[r] = EXP2(s1[r]);
            e2[r] = EXP2(s2[r]);
            e3[r] = EXP2(s3[r]);
        }
#if HK16
        // C-layout IS the K=16 B-frag layout (k = q*4+j): pack in-register.
        uint2v u00 = {pk_bf(e0[0], e0[1]), pk_bf(e0[2], e0[3])};
        uint2v u01 = {pk_bf(e1[0], e1[1]), pk_bf(e1[2], e1[3])};
        uint2v u10 = {pk_bf(e2[0], e2[1]), pk_bf(e2[2], e2[3])};
        uint2v u11 = {pk_bf(e3[0], e3[1]), pk_bf(e3[2], e3[3])};
        const bf16x4 B00 = __builtin_bit_cast(bf16x4, u00);
        const bf16x4 B01 = __builtin_bit_cast(bf16x4, u01);
        const bf16x4 B10 = __builtin_bit_cast(bf16x4, u10);
        const bf16x4 B11 = __builtin_bit_cast(bf16x4, u11);
        #pragma unroll
        for (int ct = 0; ct < 8; ++ct) {
            const bf16x8 hv = *(const bf16x8*)&HT[p][ct * 512 + lane * 8];
            const bf16x4 h0 = __builtin_shufflevector(hv, hv, 0, 1, 2, 3);
            const bf16x4 h1 = __builtin_shufflevector(hv, hv, 4, 5, 6, 7);
            acc0[ct] = mfma16(h0, B00, acc0[ct]);
            acc0[ct] = mfma16(h1, B01, acc0[ct]);
            acc1[ct] = mfma16(h0, B10, acc1[ct]);
            acc1[ct] = mfma16(h1, B11, acc1[ct]);
        }
#else
        const unsigned a01 = pk_bf(e0[0], e0[1]), a23 = pk_bf(e0[2], e0[3]);
        const unsigned b01 = pk_bf(e1[0], e1[1]), b23 = pk_bf(e1[2], e1[3]);
        const unsigned g01 = pk_bf(e2[0], e2[1]), g23 = pk_bf(e2[2], e2[3]);
        const unsigned h01 = pk_bf(e3[0], e3[1]), h23 = pk_bf(e3[2], e3[3]);
        uint4v r0, r1;
        {
            int tA, tB;
            tA = __shfl((int)a01, srcA, 64); tB = __shfl((int)b01, srcA, 64);
            r0[0] = (unsigned)(qlo ? tA : tB);
            tA = __shfl((int)a23, srcA, 64); tB = __shfl((int)b23, srcA, 64);
            r0[1] = (unsigned)(qlo ? tA : tB);
            tA = __shfl((int)a01, srcB, 64); tB = __shfl((int)b01, srcB, 64);
            r0[2] = (unsigned)(qlo ? tA : tB);
            tA = __shfl((int)a23, srcB, 64); tB = __shfl((int)b23, srcB, 64);
            r0[3] = (unsigned)(qlo ? tA : tB);
            tA = __shfl((int)g01, srcA, 64); tB = __shfl((int)h01, srcA, 64);
            r1[0] = (unsigned)(qlo ? tA : tB);
            tA = __shfl((int)g23, srcA, 64); tB = __shfl((int)h23, srcA, 64);
            r1[1] = (unsigned)(qlo ? tA : tB);
            tA = __shfl((int)g01, srcB, 64); tB = __shfl((int)h01, srcB, 64);
            r1[2] = (unsigned)(qlo ? tA : tB);
            tA = __shfl((int)g23, srcB, 64); tB = __shfl((int)h23, srcB, 64);
            r1[3] = (unsigned)(qlo ? tA : tB);
        }
        const bf16x8 bE0 = __builtin_bit_cast(bf16x8, r0);
        const bf16x8 bE1 = __builtin_bit_cast(bf16x8, r1);
        #pragma unroll
        for (int ct = 0; ct < 8; ++ct) {
            const bf16x8 aH = *(const bf16x8*)&HT[p][ct * 512 + lane * 8];
            acc0[ct] = mfma_bf16(aH, bE0, acc0[ct]);
            acc1[ct] = mfma_bf16(aH, bE1, acc1[ct]);
        }
#endif
    }
    // partial O -> global bf16 [b][nh][m 4096][c 128]
    unsigned short* P = (unsigned short*)(ws + PART_OFF);
    const size_t mb = (size_t)(b * NS + nh) * 4096 + bxm * 128;
    #pragma unroll
    for (int ct = 0; ct < 8; ++ct) {
        uint2v p0, p1;
        p0[0] = pk_bf(acc0[ct][0], acc0[ct][1]);
        p0[1] = pk_bf(acc0[ct][2], acc0[ct][3]);
        p1[0] = pk_bf(acc1[ct][0], acc1[ct][1]);
        p1[1] = pk_bf(acc1[ct][2], acc1[ct][3]);
        *(uint2v*)&P[(mb + w * 32 + l) * 128 + ct * 16 + q * 4] = p0;
        *(uint2v*)&P[(mb + w * 32 + 16 + l) * 128 + ct * 16 + q * 4] = p1;
    }
}

// ---- k4: combine NS partials + Wv projection + bias + residual ----
template<int NS>
__global__ __launch_bounds__(256) void k4_out(const float* __restrict__ x,
                                              const float* __restrict__ bv,
                                              const float* __restrict__ gamma,
                                              float* __restrict__ out,
                                              unsigned char* __restrict__ ws) {
    const int b = blockIdx.y, tid = threadIdx.x;
    const int lane = tid & 63, l = tid & 15, q = (tid >> 4) & 3, w = tid >> 6;
    const unsigned short* P = (const unsigned short*)(ws + PART_OFF);
    const unsigned short* Wvf = (const unsigned short*)(ws + WVF_OFF);
    const int mg = blockIdx.x * 64 + w * 16 + l;
    bf16x8 bO[4];
    #pragma unroll
    for (int ks = 0; ks < 4; ++ks) {
        float lo[4] = {0.f, 0.f, 0.f, 0.f}, hi[4] = {0.f, 0.f, 0.f, 0.f};
        #pragma unroll
        for (int h = 0; h < NS; ++h) {
            const size_t bh = ((size_t)(b * NS + h) * 4096 + mg) * 128;
            const uint4v u = *(const uint4v*)&P[bh + ks * 32 + q * 8];
            #pragma unroll
            for (int j = 0; j < 4; ++j) {
                lo[j] += __builtin_bit_cast(float, u[j] << 16);
                hi[j] += __builtin_bit_cast(float, u[j] & 0xffff0000u);
            }
        }
        uint4v s;
        #pragma unroll
        for (int j = 0; j < 4; ++j) s[j] = pk_bf(lo[j], hi[j]);
        bO[ks] = __builtin_bit_cast(bf16x8, s);
    }
    const float gam = gamma[0];
    const float* xb = x + b * (256 * 4096);
    float* ob = out + b * (256 * 4096);
    #pragma unroll
    for (int cct = 0; cct < 16; ++cct) {
        f32x4 f = {0.f, 0.f, 0.f, 0.f};
        #pragma unroll
        for (int ks = 0; ks < 4; ++ks) {
            const bf16x8 aV = *(const bf16x8*)&Wvf[((cct * 4 + ks) * 64 + lane) * 8];
            f = mfma_bf16(aV, bO[ks], f);
        }
        #pragma unroll
        for (int r = 0; r < 4; ++r) {
            const int cc = cct * 16 + q * 4 + r;
            ob[cc * 4096 + mg] = xb[cc * 4096 + mg] + gam * (f[r] + bv[cc]);
        }
    }
}

extern "C" void kernel_launch(void* const* d_in, const int* in_sizes, int n_in,
                              void* d_out, int out_size, void* d_ws, size_t ws_size,
                              hipStream_t stream) {
    const float* x   = (const float*)d_in[0];
    const float* wf  = (const float*)d_in[1];
    const float* bfv = (const float*)d_in[2];
    const float* wg  = (const float*)d_in[3];
    const float* bg  = (const float*)d_in[4];
    const float* wh  = (const float*)d_in[5];
    const float* bh  = (const float*)d_in[6];
    const float* wv  = (const float*)d_in[7];
    const float* bv  = (const float*)d_in[8];
    const float* gam = (const float*)d_in[9];
    float* out = (float*)d_out;
    unsigned char* ws = (unsigned char*)d_ws;
    (void)in_sizes; (void)n_in; (void)out_size;

    hipLaunchKernelGGL(k0_pack, dim3(321), dim3(256), 0, stream,
                       wf, bfv, wg, bg, wh, bh, wv, ws);
    hipLaunchKernelGGL(k1_proj, dim3(64, 8), dim3(256), 0, stream, x, ws);
    hipLaunchKernelGGL(k2_stats, dim3(16, 8, 4), dim3(256), 0, stream, ws);

    const size_t base = (size_t)PART_OFF;
    const size_t per  = (size_t)8 * 4096 * 128 * 2;   // bytes per NS slice
    if (ws_size >= base + 4 * per) {
        hipLaunchKernelGGL(HIP_KERNEL_NAME(k3_attn<4>), dim3(1024), dim3(256),
                           0, stream, ws);
        hipLaunchKernelGGL(HIP_KERNEL_NAME(k4_out<4>), dim3(64, 8), dim3(256),
                           0, stream, x, bv, gam, out, ws);
    } else {
        hipLaunchKernelGGL(HIP_KERNEL_NAME(k3_attn<2>), dim3(512), dim3(256),
                           0, stream, ws);
        hipLaunchKernelGGL(HIP_KERNEL_NAME(k4_out<2>), dim3(64, 8), dim3(256),
                           0, stream, x, bv, gam, out, ws);
    }
}